// Round 19
// baseline (73.073 us; speedup 1.0000x reference)
//
#include <hip/hip_runtime.h>
#include <float.h>

#define NSEG 8
#define SEGLEN 1024   // B*Ls*H*D = 1*4*8*32
#define BIGV 1e30f    // "infinity" for invalid DP cells
#define PADV 1e18f    // x-pad sentinel: huge cost; garbage stays < 1e21

#define NW 4          // waves per block (256 threads); wave owns 256 cols
#define CH 64         // steps per chunk (one flag handshake per chunk)
#define NCH 18        // steps 0..1151 (lane 63: row 1023 at t=1149, skew 2/lane)
#define XLEN 1216     // xl[t] = x[t] for t<1024, else PADV (read up to 1153)
#define BOFF 128      // bnd[w][row + 128]
#define BSTRIDE 1288  // max read index 64*17+BOFF+2+63 = 1281; write max 1153

#define DPPF(OLD, SRC, CTRL, RM, BM, BC)                                      \
    __int_as_float(__builtin_amdgcn_update_dpp(                               \
        __float_as_int(OLD), __float_as_int(SRC), CTRL, RM, BM, BC))
// lane i <- lane i-1; lane 0 <- OLD[lane 0]   (validated R2-R18)
#define WSHIFT1(OLD, SRC) DPPF(OLD, SRC, 0x138, 0xF, 0xF, false)

__device__ __forceinline__ float readlaneF(float v, int l) {
    return __int_as_float(__builtin_amdgcn_readlane(__float_as_int(v), l));
}

// SKEW-2 DELAY-REGISTER systolic DTW, 4 waves (1 per SIMD). Wave w owns cols
// [256w,256w+256); lane L owns c_e = 256w+4L+e, e in 0..3.
// At step t, lane L computes ROW r = t - 2L (skew 2 per lane). The left
// neighbor's value for row r was produced by lane L-1 at ITS step t-2, so
// the wf_sr1 shift runs at the END of step t-2 and the value waits one full
// step in a delay register (lfB -> lf rotation = free renaming in unrolled
// code). Same for x (xB -> xA). Result: NO DPP on the inter-step critical
// cycle -- the only recurrence is c_e(t) -> c_e(t+1) (one min3+add), so the
// unrolled steps software-pipeline against the ~21-inst issue budget.
// (R18's RS=2 doubled the on-chain DPPs and regressed; R10-R18 evidence:
// each on-chain wf_sr1 costs ~45 cyc/step.)
// Cells (d-form; scan-form rejected R13/R16):
//   c0 = |x[r]-y0| + min3(Q0(up), lf(left r), dgl(left r-1))
//   c_e = |x[r]-y_e| + min3(Q_e, c_{e-1}, Q_{e-1})
// Rotation per step: dgl=lf; lf=lfB; lfB=shift(bp, c3); xA=xB; xB=shift(xp, xA).
// Inject leads are +2 (consumed 2 steps after shift): bv = br[64tc+BOFF+2+lane]
// (rows 64tc+2..64tc+65), xv = xl[64tc+2+lane] (x[64tc+2..64tc+65]).
// x inits are PADV for lanes>0 (garbage rows must carry huge costs -- R12
// poisoning rule); lf/dgl inits are uniform boundary reads (harmless: any
// garbage-row cell cost >= 1e18 dominates).
// Lane 63 writes c3 (row r = t-126) to bnd[wv+1][t+2] each step; others hit
// a dump sink (branchless). Monotone chunk-counter handshake: consumer chunk
// tc reads rows <= 64tc+65 -> producer chunk tc+2 done -> flag >= tc+3.
__global__ __launch_bounds__(256) void dtw_d2_kernel(const float* __restrict__ q,
                                                     const float* __restrict__ kk,
                                                     float* __restrict__ dists) {
    __shared__ float xl[XLEN];
    __shared__ float bnd[NW + 1][BSTRIDE];  // bnd[0] = BIGV region for wave 0
    __shared__ float dump[128];             // sink, indices up to 125 (R8 lesson)
    __shared__ int flagsA[NW + 1];          // [0]=sentinel; [w+1]=wave w chunks done
    const int tid = threadIdx.x;
    const int lane = tid & 63;
    const int wv = tid >> 6;
    const int pair = blockIdx.x;            // 0..63
    const float* __restrict__ x = q + (pair >> 3) * SEGLEN;
    const float* __restrict__ y = kk + (pair & 7) * SEGLEN;

    for (int t = tid; t < XLEN; t += 256) xl[t] = (t < SEGLEN) ? x[t] : PADV;
    // flat index 127 = bnd[0][BOFF-1] = virtual corner D[-1,-1] = 0; rest BIGV.
    for (int t = tid; t < (NW + 1) * BSTRIDE; t += 256)
        (&bnd[0][0])[t] = (t == BOFF - 1) ? 0.f : BIGV;
    if (tid < NW + 1) flagsA[tid] = (tid == 0) ? 0x7FFFFFFF : 0;

    const float4 y4 = *(const float4*)(y + wv * 256 + lane * 4);
    const float yv0 = y4.x, yv1 = y4.y, yv2 = y4.z, yv3 = y4.w;

    __syncthreads();   // the only block-wide barrier

    const float* __restrict__ br = &bnd[wv][0];   // left neighbor's boundary

    // wait for the first 2 producer chunks (init reads rows -1..1; row 1 is
    // written at producer step 127 -> its chunk 1 -> flag >= 2)
    {
        const int need0 = (NCH < 2) ? NCH : 2;
        while (__hip_atomic_load(&flagsA[wv], __ATOMIC_ACQUIRE,
                                 __HIP_MEMORY_SCOPE_WORKGROUP) < need0)
            __builtin_amdgcn_s_sleep(1);
    }
    float Q0 = BIGV, Q1 = BIGV, Q2 = BIGV, Q3 = BIGV;  // row r-1 of own cols
    const float x0u = xl[0], x1u = xl[1];
    float xA = (lane == 0) ? x0u : PADV;   // x[r] (delay reg, consume now)
    float xB = (lane == 0) ? x1u : PADV;   // x[r+1] (arriving)
    float lf  = br[BOFF];      // left col row r   (lane 0 real; others garbage-safe)
    float lfB = br[BOFF + 1];  // left col row r+1 (arriving)
    float dgl = br[BOFF - 1];  // left col row r-1 (wave 0: corner 0)

// One step with pre-hoisted inject values xp (x) and bp (boundary).
#define STEP(s, xp, bp) {                                                     \
    const float c0 = fabsf(xA - yv0) + fminf(fminf(Q0, lf), dgl);             \
    const float c1 = fabsf(xA - yv1) + fminf(fminf(Q1, c0), Q0);              \
    const float c2 = fabsf(xA - yv2) + fminf(fminf(Q2, c1), Q1);              \
    const float c3 = fabsf(xA - yv3) + fminf(fminf(Q3, c2), Q2);              \
    const float tL = WSHIFT1(bp, c3);                                         \
    const float tX = WSHIFT1(xp, xA);                                         \
    va[(s)] = c3;                                                             \
    dgl = lf; lf = lfB; lfB = tL;                                             \
    xA = xB; xB = tX;                                                         \
    Q0 = c0; Q1 = c1; Q2 = c2; Q3 = c3;                                       \
}
// 8-step group: hoist all 16 readlanes to the top (R15 win: SGPR hazards and
// s->v movs amortize away from the dependent DPPs).
#define STEP8(s) {                                                            \
    const float xp0 = readlaneF(xv, (s)+0), xp1 = readlaneF(xv, (s)+1);       \
    const float xp2 = readlaneF(xv, (s)+2), xp3 = readlaneF(xv, (s)+3);       \
    const float xp4 = readlaneF(xv, (s)+4), xp5 = readlaneF(xv, (s)+5);       \
    const float xp6 = readlaneF(xv, (s)+6), xp7 = readlaneF(xv, (s)+7);       \
    const float bp0 = readlaneF(bvv, (s)+0), bp1 = readlaneF(bvv, (s)+1);     \
    const float bp2 = readlaneF(bvv, (s)+2), bp3 = readlaneF(bvv, (s)+3);     \
    const float bp4 = readlaneF(bvv, (s)+4), bp5 = readlaneF(bvv, (s)+5);     \
    const float bp6 = readlaneF(bvv, (s)+6), bp7 = readlaneF(bvv, (s)+7);     \
    STEP((s)+0, xp0, bp0) STEP((s)+1, xp1, bp1)                               \
    STEP((s)+2, xp2, bp2) STEP((s)+3, xp3, bp3)                               \
    STEP((s)+4, xp4, bp4) STEP((s)+5, xp5, bp5)                               \
    STEP((s)+6, xp6, bp6) STEP((s)+7, xp7, bp7)                               \
}

#pragma unroll 1
    for (int tc = 0; tc < NCH; ++tc) {
        // consumer chunk tc reads bnd rows <= 64tc+65; producer covers row
        // 64tc+65 at its step 64tc+191 -> chunk tc+2 -> flag >= tc+3,
        // capped at NCH (later rows are BIGV pad).
        const int need = (tc + 3 < NCH) ? (tc + 3) : NCH;
        while (__hip_atomic_load(&flagsA[wv], __ATOMIC_ACQUIRE,
                                 __HIP_MEMORY_SCOPE_WORKGROUP) < need)
            __builtin_amdgcn_s_sleep(1);

        const float xv = xl[64 * tc + 2 + lane];          // x[64tc+2+j] (+2 lead)
        const float bvv = br[64 * tc + BOFF + 2 + lane];  // bnd row 64tc+2+j
        // boundary write: lane 63 (row r = t-126) -> bnd[wv+1][64tc+2+s];
        // others -> dump.
        float* va = (lane == 63) ? &bnd[wv + 1][64 * tc + 2] : &dump[lane];

        STEP8(0) STEP8(8) STEP8(16) STEP8(24) STEP8(32) STEP8(40) STEP8(48) STEP8(56)

        // publish chunk tc (release orders the ds_writes above before the flag)
        __hip_atomic_store(&flagsA[wv + 1], tc + 1, __ATOMIC_RELEASE,
                           __HIP_MEMORY_SCOPE_WORKGROUP);
    }
#undef STEP
#undef STEP8

    // D[1023,1023]: wave 3 lane 63 col e=3 at t=1149 (chunk 17, s=61) -> c3
    // -> bnd[NW][1151]; registers continue with garbage rows, so read LDS.
    if (wv == NW - 1 && lane == 0) dists[pair] = bnd[NW][1151];
}

// out[i*1024+p] = sum_j softmax_j(0.5*dists[i,:])[j] * values[j*1024+p]
__global__ __launch_bounds__(256) void softmax_out_kernel(const float* __restrict__ v,
                                                          const float* __restrict__ dists,
                                                          float* __restrict__ out) {
    const int o = blockIdx.x * blockDim.x + threadIdx.x;
    if (o >= NSEG * SEGLEN) return;
    const int i = o >> 10;
    const int p = o & 1023;

    float l[NSEG];
    float mx = -FLT_MAX;
#pragma unroll
    for (int j = 0; j < NSEG; ++j) {
        l[j] = 0.5f * dists[i * NSEG + j];
        mx = fmaxf(mx, l[j]);
    }
    float s = 0.f;
#pragma unroll
    for (int j = 0; j < NSEG; ++j) {
        l[j] = expf(l[j] - mx);
        s += l[j];
    }
    const float inv = 1.f / s;
    float acc = 0.f;
#pragma unroll
    for (int j = 0; j < NSEG; ++j) acc += (l[j] * inv) * v[j * SEGLEN + p];
    out[o] = acc;
}

extern "C" void kernel_launch(void* const* d_in, const int* in_sizes, int n_in,
                              void* d_out, int out_size, void* d_ws, size_t ws_size,
                              hipStream_t stream) {
    const float* q = (const float*)d_in[0];   // queries [1,32,8,32] f32
    const float* k = (const float*)d_in[1];   // keys
    const float* v = (const float*)d_in[2];   // values
    float* out = (float*)d_out;               // [8192] f32
    float* dists = (float*)d_ws;              // 64 floats scratch

    dtw_d2_kernel<<<dim3(NSEG * NSEG), dim3(256), 0, stream>>>(q, k, dists);
    softmax_out_kernel<<<dim3((NSEG * SEGLEN + 255) / 256), dim3(256), 0, stream>>>(v, dists, out);
}

// Round 20
// 72.873 us; speedup vs baseline: 1.0027x; 1.0027x over previous
//
#include <hip/hip_runtime.h>
#include <float.h>

#define NSEG 8
#define SEGLEN 1024   // B*Ls*H*D = 1*4*8*32
#define BIGV 1e30f    // "infinity" for invalid DP cells
#define PADV 1e18f    // x-pad sentinel: huge cost; garbage stays < 1e21

#define NW 4          // waves per block (256 threads); wave owns 256 cols
#define CH 64         // steps per chunk (one flag handshake per chunk)
#define NCH 18        // steps 0..1151 (lane 63: row 1023 at t=1149, skew 2/lane)
#define XLEN 1216     // xl[t] = x[t] for t<1024, else PADV (read up to 1153)
#define BOFF 128      // bnd[w][row + 128]
#define BSTRIDE 1288  // max read index 64*17+BOFF+2+63 = 1281; write max 1153

#define DPPF(OLD, SRC, CTRL, RM, BM, BC)                                      \
    __int_as_float(__builtin_amdgcn_update_dpp(                               \
        __float_as_int(OLD), __float_as_int(SRC), CTRL, RM, BM, BC))
// lane i <- lane i-1; lane 0 <- OLD[lane 0]   (validated R2-R19)
#define WSHIFT1(OLD, SRC) DPPF(OLD, SRC, 0x138, 0xF, 0xF, false)
// stream advance (wf_sl1): lane i <- lane i+1; lane 63 keeps stale value.
// Only lane 0 of a stream is ever consumed (as a DPP old-operand).
#define WSTREAM(SRC) DPPF(SRC, SRC, 0x130, 0xF, 0xF, false)

// SKEW-2 DELAY-REGISTER systolic DTW, 4 waves (1 per SIMD). Wave w owns cols
// [256w,256w+256); lane L owns c_e = 256w+4L+e, e in 0..3.
// At step t, lane L computes ROW r = t - 2L. Left-neighbor values arrive via
// a wf_sr1 issued at the END of step t-2 and wait one step in a delay
// register (lfB -> lf rotation = free renaming in unrolled code); same for x.
// R20 (A/B vs R19, single variable): the inject values are delivered by
// WSTREAM register streams instead of readlane+mov -- bstr/xstr hold row
// 64tc+2+lane at lane `lane`; one wf_sl1 advance per step keeps the current
// inject at lane 0, consumed directly as the DPP old-operand. ZERO SGPR
// traffic in the hot loop (R19's 16 readlanes + 16 s->v movs per 8 steps
// carried VALU->SGPR hazard wait-states). Stream-advance DPPs are off-chain
// here (>= 1 full step of slack) unlike R7/R13 where they were consumed
// same-step and regressed.
// Cells (d-form): c0 = |x[r]-y0| + min3(Q0, lf, dgl);
//                 c_e = |x[r]-y_e| + min3(Q_e, c_{e-1}, Q_{e-1})
// Rotation: dgl=lf; lf=lfB; lfB=shift(bstr, c3); xA=xB; xB=shift(xstr, xA).
// Garbage rows (r<0, r>1023) carry PADV-scale costs acting as +inf.
// Lane 63 writes c3 (row r = t-126) to bnd[wv+1][t+2]; others hit a dump
// sink (branchless). Monotone chunk-counter handshake: consumer chunk tc
// reads rows <= 64tc+65 -> producer chunk tc+2 done -> flag >= tc+3.
__global__ __launch_bounds__(256) void dtw_d2_kernel(const float* __restrict__ q,
                                                     const float* __restrict__ kk,
                                                     float* __restrict__ dists) {
    __shared__ float xl[XLEN];
    __shared__ float bnd[NW + 1][BSTRIDE];  // bnd[0] = BIGV region for wave 0
    __shared__ float dump[128];             // sink, indices up to 125 (R8 lesson)
    __shared__ int flagsA[NW + 1];          // [0]=sentinel; [w+1]=wave w chunks done
    const int tid = threadIdx.x;
    const int lane = tid & 63;
    const int wv = tid >> 6;
    const int pair = blockIdx.x;            // 0..63
    const float* __restrict__ x = q + (pair >> 3) * SEGLEN;
    const float* __restrict__ y = kk + (pair & 7) * SEGLEN;

    for (int t = tid; t < XLEN; t += 256) xl[t] = (t < SEGLEN) ? x[t] : PADV;
    // flat index 127 = bnd[0][BOFF-1] = virtual corner D[-1,-1] = 0; rest BIGV.
    for (int t = tid; t < (NW + 1) * BSTRIDE; t += 256)
        (&bnd[0][0])[t] = (t == BOFF - 1) ? 0.f : BIGV;
    if (tid < NW + 1) flagsA[tid] = (tid == 0) ? 0x7FFFFFFF : 0;

    const float4 y4 = *(const float4*)(y + wv * 256 + lane * 4);
    const float yv0 = y4.x, yv1 = y4.y, yv2 = y4.z, yv3 = y4.w;

    __syncthreads();   // the only block-wide barrier

    const float* __restrict__ br = &bnd[wv][0];   // left neighbor's boundary

    // wait for the first 2 producer chunks (init reads rows -1..1; row 1 is
    // written at producer step 127 -> its chunk 1 -> flag >= 2)
    {
        const int need0 = (NCH < 2) ? NCH : 2;
        while (__hip_atomic_load(&flagsA[wv], __ATOMIC_ACQUIRE,
                                 __HIP_MEMORY_SCOPE_WORKGROUP) < need0)
            __builtin_amdgcn_s_sleep(1);
    }
    float Q0 = BIGV, Q1 = BIGV, Q2 = BIGV, Q3 = BIGV;  // row r-1 of own cols
    const float x0u = xl[0], x1u = xl[1];
    float xA = (lane == 0) ? x0u : PADV;   // x[r] (delay reg, consume now)
    float xB = (lane == 0) ? x1u : PADV;   // x[r+1] (arriving)
    float lf  = br[BOFF];      // left col row r   (lane 0 real; others garbage-safe)
    float lfB = br[BOFF + 1];  // left col row r+1 (arriving)
    float dgl = br[BOFF - 1];  // left col row r-1 (wave 0: corner 0)

// One step. Injects come from the stream registers' lane 0 (DPP old-operand);
// streams advance one lane afterwards. No SGPR ops.
#define STEP(s) {                                                             \
    const float c0 = fabsf(xA - yv0) + fminf(fminf(Q0, lf), dgl);             \
    const float c1 = fabsf(xA - yv1) + fminf(fminf(Q1, c0), Q0);              \
    const float c2 = fabsf(xA - yv2) + fminf(fminf(Q2, c1), Q1);              \
    const float c3 = fabsf(xA - yv3) + fminf(fminf(Q3, c2), Q2);              \
    const float tL = WSHIFT1(bstr, c3);                                       \
    const float tX = WSHIFT1(xstr, xA);                                       \
    bstr = WSTREAM(bstr);                                                     \
    xstr = WSTREAM(xstr);                                                     \
    va[(s)] = c3;                                                             \
    dgl = lf; lf = lfB; lfB = tL;                                             \
    xA = xB; xB = tX;                                                         \
    Q0 = c0; Q1 = c1; Q2 = c2; Q3 = c3;                                       \
}
#define STEP8(s) STEP(s) STEP((s)+1) STEP((s)+2) STEP((s)+3)                  \
                 STEP((s)+4) STEP((s)+5) STEP((s)+6) STEP((s)+7)

#pragma unroll 1
    for (int tc = 0; tc < NCH; ++tc) {
        // consumer chunk tc reads bnd rows <= 64tc+65; producer covers row
        // 64tc+65 at its step 64tc+191 -> chunk tc+2 -> flag >= tc+3,
        // capped at NCH (later rows are BIGV pad).
        const int need = (tc + 3 < NCH) ? (tc + 3) : NCH;
        while (__hip_atomic_load(&flagsA[wv], __ATOMIC_ACQUIRE,
                                 __HIP_MEMORY_SCOPE_WORKGROUP) < need)
            __builtin_amdgcn_s_sleep(1);

        // stream registers: row 64tc+2+lane at lane `lane`; step s consumes
        // lane 0 (= row/x index 64tc+2+s, the +2 lead validated R17->R18).
        float xstr = xl[64 * tc + 2 + lane];
        float bstr = br[64 * tc + BOFF + 2 + lane];
        // boundary write: lane 63 (row r = t-126) -> bnd[wv+1][64tc+2+s];
        // others -> dump.
        float* va = (lane == 63) ? &bnd[wv + 1][64 * tc + 2] : &dump[lane];

        STEP8(0) STEP8(8) STEP8(16) STEP8(24) STEP8(32) STEP8(40) STEP8(48) STEP8(56)

        // publish chunk tc (release orders the ds_writes above before the flag)
        __hip_atomic_store(&flagsA[wv + 1], tc + 1, __ATOMIC_RELEASE,
                           __HIP_MEMORY_SCOPE_WORKGROUP);
    }
#undef STEP
#undef STEP8

    // D[1023,1023]: wave 3 lane 63 col e=3 at t=1149 (chunk 17, s=61) -> c3
    // -> bnd[NW][1151]; registers continue with garbage rows, so read LDS.
    if (wv == NW - 1 && lane == 0) dists[pair] = bnd[NW][1151];
}

// out[i*1024+p] = sum_j softmax_j(0.5*dists[i,:])[j] * values[j*1024+p]
__global__ __launch_bounds__(256) void softmax_out_kernel(const float* __restrict__ v,
                                                          const float* __restrict__ dists,
                                                          float* __restrict__ out) {
    const int o = blockIdx.x * blockDim.x + threadIdx.x;
    if (o >= NSEG * SEGLEN) return;
    const int i = o >> 10;
    const int p = o & 1023;

    float l[NSEG];
    float mx = -FLT_MAX;
#pragma unroll
    for (int j = 0; j < NSEG; ++j) {
        l[j] = 0.5f * dists[i * NSEG + j];
        mx = fmaxf(mx, l[j]);
    }
    float s = 0.f;
#pragma unroll
    for (int j = 0; j < NSEG; ++j) {
        l[j] = expf(l[j] - mx);
        s += l[j];
    }
    const float inv = 1.f / s;
    float acc = 0.f;
#pragma unroll
    for (int j = 0; j < NSEG; ++j) acc += (l[j] * inv) * v[j * SEGLEN + p];
    out[o] = acc;
}

extern "C" void kernel_launch(void* const* d_in, const int* in_sizes, int n_in,
                              void* d_out, int out_size, void* d_ws, size_t ws_size,
                              hipStream_t stream) {
    const float* q = (const float*)d_in[0];   // queries [1,32,8,32] f32
    const float* k = (const float*)d_in[1];   // keys
    const float* v = (const float*)d_in[2];   // values
    float* out = (float*)d_out;               // [8192] f32
    float* dists = (float*)d_ws;              // 64 floats scratch

    dtw_d2_kernel<<<dim3(NSEG * NSEG), dim3(256), 0, stream>>>(q, k, dists);
    softmax_out_kernel<<<dim3((NSEG * SEGLEN + 255) / 256), dim3(256), 0, stream>>>(v, dists, out);
}

// Round 21
// 63.923 us; speedup vs baseline: 1.1431x; 1.1400x over previous
//
#include <hip/hip_runtime.h>
#include <float.h>

#define NSEG 8
#define SEGLEN 1024   // B*Ls*H*D = 1*4*8*32
#define BIGV 1e30f    // "infinity" for invalid DP cells
#define PADV 1e18f    // x-pad sentinel: huge cost, no overflow over a chunk

#define NW 4          // waves per block (256 threads); wave owns 256 cols
#define CH 64         // steps per chunk (one flag handshake per chunk)
#define NCH 17        // local steps 0..1087 (lane 63 hits row 1023 at t=1086)
#define XLEN 1152     // xl[t] = x[t] for t<1024, else PADV (read up to 1087)
#define BSTRIDE 1160  // bnd[w][r+64] = D[r, 256w-1]; max read index 1152

#define DPPF(OLD, SRC, CTRL, RM, BM, BC)                                      \
    __int_as_float(__builtin_amdgcn_update_dpp(                               \
        __float_as_int(OLD), __float_as_int(SRC), CTRL, RM, BM, BC))
// lane i <- lane i-1; lane 0 <- OLD[lane 0]   (validated R2-R20)
#define WSHIFT1(OLD, SRC) DPPF(OLD, SRC, 0x138, 0xF, 0xF, false)

__device__ __forceinline__ float readlaneF(float v, int l) {
    return __int_as_float(__builtin_amdgcn_readlane(__float_as_int(v), l));
}

// Lane-skewed systolic DTW, 4 waves (1 per SIMD). Wave w owns cols
// [256w,256w+256); lane L owns c_e = 256w+4L+e, e in 0..3.
// At local step t, lane L computes ROW r = t - L of its four columns.
// R21 (single-variable A/B vs R15): the min3 is reassociated so the FRESH
// value enters the OUTER fmin:
//   m0 = min(P0, dgl); m_e = min(P_e, P_{e-1})   [all last-step, off-chain]
//   c0 = |x-y0| + min(m0, lf);  c_e = |x-y_e| + min(m_e, c_{e-1})
// Same instruction count as R15 (2 fmin + sub + add per cell), exact same
// math (min associative), but the serial chain is 2 ops/cell (fmin+add)
// instead of 3 -> 8 dependent ops/step vs 12. R12-R20's invariant ~95
// cyc/step tracks the 12-op chain at ~8 cyc/dep-op; this should break it.
// Injects: R15's group-hoisted readlanes (best measured). Rows r<0 / r>1023
// compute garbage >= 1e18 (PADV costs) acting as +inf.
// Cross-wave boundary: lane 63 writes D[r,256w+255] to bnd[w+1][r+64] each
// step (others hit a dump sink, branchless); monotone chunk-counter
// handshake with lag 2 (consumer chunk tc reads rows <= 64tc+64).
__global__ __launch_bounds__(256) void dtw_sk4_kernel(const float* __restrict__ q,
                                                      const float* __restrict__ kk,
                                                      float* __restrict__ dists) {
    __shared__ float xl[XLEN];
    __shared__ float bnd[NW + 1][BSTRIDE];  // bnd[0] = BIGV region for wave 0
    __shared__ float dump[128];             // sink, indices up to 125 (R8 lesson)
    __shared__ int flagsA[NW + 1];          // [0]=sentinel; [w+1]=wave w chunks done
    const int tid = threadIdx.x;
    const int lane = tid & 63;
    const int wv = tid >> 6;
    const int pair = blockIdx.x;            // 0..63
    const float* __restrict__ x = q + (pair >> 3) * SEGLEN;
    const float* __restrict__ y = kk + (pair & 7) * SEGLEN;

    for (int t = tid; t < XLEN; t += 256) xl[t] = (t < SEGLEN) ? x[t] : PADV;
    // flat index 63 = bnd[0][63] = virtual corner D[-1,-1] = 0; rest BIGV.
    for (int t = tid; t < (NW + 1) * BSTRIDE; t += 256)
        (&bnd[0][0])[t] = (t == 63) ? 0.f : BIGV;
    if (tid < NW + 1) flagsA[tid] = (tid == 0) ? 0x7FFFFFFF : 0;

    const float4 y4 = *(const float4*)(y + wv * 256 + lane * 4);
    const float yv0 = y4.x, yv1 = y4.y, yv2 = y4.z, yv3 = y4.w;

    __syncthreads();   // the only block-wide barrier

    const float* __restrict__ br = &bnd[wv][0];   // left neighbor's boundary

    // wait for the first 2 producer chunks before reading init boundary
    {
        const int need0 = (NCH < 2) ? NCH : 2;
        while (__hip_atomic_load(&flagsA[wv], __ATOMIC_ACQUIRE,
                                 __HIP_MEMORY_SCOPE_WORKGROUP) < need0)
            __builtin_amdgcn_s_sleep(1);
    }
    float P0 = BIGV, P1 = BIGV, P2 = BIGV, P3 = BIGV, xreg = PADV;
    float lf = br[64];    // D[0, 256w-1] (wave 0: BIGV); real only for lane 0
    float dgl = br[63];   // D[-1,256w-1] (wave 0: corner 0)

// One systolic step with pre-hoisted inject values xp (x) and bp (boundary).
// m_e precomputed from last-step values; fresh operand in the OUTER fmin.
#define STEP(s, xp, bp) {                                                     \
    xreg = WSHIFT1(xp, xreg);                                                 \
    const float m0 = fminf(P0, dgl);                                          \
    const float m1 = fminf(P1, P0);                                           \
    const float m2 = fminf(P2, P1);                                           \
    const float m3 = fminf(P3, P2);                                           \
    const float c0n = fabsf(xreg - yv0) + fminf(m0, lf);                      \
    const float c1n = fabsf(xreg - yv1) + fminf(m1, c0n);                     \
    const float c2n = fabsf(xreg - yv2) + fminf(m2, c1n);                     \
    const float c3n = fabsf(xreg - yv3) + fminf(m3, c2n);                     \
    const float n1 = WSHIFT1(bp, c3n);                                        \
    dgl = lf; lf = n1; P0 = c0n; P1 = c1n; P2 = c2n; P3 = c3n;                \
    va[(s)] = c3n;                                                            \
}
// 8-step group: hoist all 16 readlanes to the top so the SGPR hazards and
// s->v movs amortize and schedule away from the dependent DPPs (R15 win).
#define STEP8(s) {                                                            \
    const float xp0 = readlaneF(xv, (s)+0), xp1 = readlaneF(xv, (s)+1);       \
    const float xp2 = readlaneF(xv, (s)+2), xp3 = readlaneF(xv, (s)+3);       \
    const float xp4 = readlaneF(xv, (s)+4), xp5 = readlaneF(xv, (s)+5);       \
    const float xp6 = readlaneF(xv, (s)+6), xp7 = readlaneF(xv, (s)+7);       \
    const float bp0 = readlaneF(bvv, (s)+0), bp1 = readlaneF(bvv, (s)+1);     \
    const float bp2 = readlaneF(bvv, (s)+2), bp3 = readlaneF(bvv, (s)+3);     \
    const float bp4 = readlaneF(bvv, (s)+4), bp5 = readlaneF(bvv, (s)+5);     \
    const float bp6 = readlaneF(bvv, (s)+6), bp7 = readlaneF(bvv, (s)+7);     \
    STEP((s)+0, xp0, bp0) STEP((s)+1, xp1, bp1)                               \
    STEP((s)+2, xp2, bp2) STEP((s)+3, xp3, bp3)                               \
    STEP((s)+4, xp4, bp4) STEP((s)+5, xp5, bp5)                               \
    STEP((s)+6, xp6, bp6) STEP((s)+7, xp7, bp7)                               \
}

#pragma unroll 1
    for (int tc = 0; tc < NCH; ++tc) {
        // consumer chunk tc reads bnd rows <= 64tc+64 (index 64tc+128);
        // producer writes row r at its step r+63 -> needs chunk tc+1 done
        // (flag >= tc+2), capped at NCH (later indices are BIGV pad).
        const int need = (tc + 2 < NCH) ? (tc + 2) : NCH;
        while (__hip_atomic_load(&flagsA[wv], __ATOMIC_ACQUIRE,
                                 __HIP_MEMORY_SCOPE_WORKGROUP) < need)
            __builtin_amdgcn_s_sleep(1);

        const float xv = xl[CH * tc + lane];         // x[64tc+s] inject stream
        const float bvv = br[CH * tc + 65 + lane];   // inject: bnd row 64tc+s+1
        // boundary write: lane 63 -> bnd[wv+1][64tc+1+s]; others -> dump
        float* va = (lane == 63) ? &bnd[wv + 1][CH * tc + 1] : &dump[lane];

        STEP8(0) STEP8(8) STEP8(16) STEP8(24) STEP8(32) STEP8(40) STEP8(48) STEP8(56)

        // publish chunk tc (release orders the ds_writes above before the flag)
        __hip_atomic_store(&flagsA[wv + 1], tc + 1, __ATOMIC_RELEASE,
                           __HIP_MEMORY_SCOPE_WORKGROUP);
    }
#undef STEP
#undef STEP8

    // D[1023,1023]: wave 3 lane 63 col e=3 at t=1086 -> bnd[NW][1087]
    // (t=1087 overwrites P3 with a garbage row, so read back from LDS).
    if (wv == NW - 1 && lane == 0) dists[pair] = bnd[NW][1087];
}

// out[i*1024+p] = sum_j softmax_j(0.5*dists[i,:])[j] * values[j*1024+p]
__global__ __launch_bounds__(256) void softmax_out_kernel(const float* __restrict__ v,
                                                          const float* __restrict__ dists,
                                                          float* __restrict__ out) {
    const int o = blockIdx.x * blockDim.x + threadIdx.x;
    if (o >= NSEG * SEGLEN) return;
    const int i = o >> 10;
    const int p = o & 1023;

    float l[NSEG];
    float mx = -FLT_MAX;
#pragma unroll
    for (int j = 0; j < NSEG; ++j) {
        l[j] = 0.5f * dists[i * NSEG + j];
        mx = fmaxf(mx, l[j]);
    }
    float s = 0.f;
#pragma unroll
    for (int j = 0; j < NSEG; ++j) {
        l[j] = expf(l[j] - mx);
        s += l[j];
    }
    const float inv = 1.f / s;
    float acc = 0.f;
#pragma unroll
    for (int j = 0; j < NSEG; ++j) acc += (l[j] * inv) * v[j * SEGLEN + p];
    out[o] = acc;
}

extern "C" void kernel_launch(void* const* d_in, const int* in_sizes, int n_in,
                              void* d_out, int out_size, void* d_ws, size_t ws_size,
                              hipStream_t stream) {
    const float* q = (const float*)d_in[0];   // queries [1,32,8,32] f32
    const float* k = (const float*)d_in[1];   // keys
    const float* v = (const float*)d_in[2];   // values
    float* out = (float*)d_out;               // [8192] f32
    float* dists = (float*)d_ws;              // 64 floats scratch

    dtw_sk4_kernel<<<dim3(NSEG * NSEG), dim3(256), 0, stream>>>(q, k, dists);
    softmax_out_kernel<<<dim3((NSEG * SEGLEN + 255) / 256), dim3(256), 0, stream>>>(v, dists, out);
}

// Round 22
// 55.472 us; speedup vs baseline: 1.3173x; 1.1523x over previous
//
#include <hip/hip_runtime.h>
#include <float.h>

#define NSEG 8
#define SEGLEN 1024   // B*Ls*H*D = 1*4*8*32
#define BIGV 1e30f    // "infinity" for invalid DP cells
#define PADV 1e18f    // x-pad sentinel: huge cost, no overflow over a chunk

#define NW 4          // waves per block (256 threads); wave owns 256 cols
#define CH 64         // steps per chunk (one flag handshake per chunk)
#define NCH 17        // local steps 0..1087 (lane 63 hits row 1023 at t=1086)
#define XLEN 1152     // xl[t] = x[t] for t<1024, else PADV
#define BOFF 67       // bnd[w][row + 67]; 67 chosen so preload base 64tc+68
                      // is 16B-aligned (uniform ds_read_b128)
#define BSTRIDE 1160  // max read index 64*16+68+63 = 1155

#define DPPF(OLD, SRC, CTRL, RM, BM, BC)                                      \
    __int_as_float(__builtin_amdgcn_update_dpp(                               \
        __float_as_int(OLD), __float_as_int(SRC), CTRL, RM, BM, BC))
// lane i <- lane i-1; lane 0 <- OLD[lane 0]   (validated R2-R21)
#define WSHIFT1(OLD, SRC) DPPF(OLD, SRC, 0x138, 0xF, 0xF, false)

// Lane-skewed systolic DTW, 4 waves (1 per SIMD). Wave w owns cols
// [256w,256w+256); lane L owns c_e = 256w+4L+e, e in 0..3.
// At local step t, lane L computes ROW r = t - L of its four columns:
//   c0 = |x[r]-y0| + min3(P0(up), lf(left), dgl(diag))
//   c_e = |x[r]-y_e| + min3(P_e, c_{e-1}, P_{e-1})
// lf/dgl arrive via one end-of-step wf_sr1 of c3; x travels systolically the
// same way.
// R22: measured law across R9-R21 is cyc/step ~ 4.4 x inst/step (single-wave
// issue cadence floor; chain/SGPR/DPP theories all nulled by A/B). So this
// round only DELETES instructions: both inject values are wave-uniform, so
// each chunk preloads 64 x values and 64 boundary rows into static-indexed
// register arrays via 32 uniform ds_read_b128 (0.5 inst/step) replacing the
// 32 readlane+mov per 8-step group (4 inst/step). DPP old-operands read the
// arrays directly. Values/timing bit-identical to R21; VGPR ~172 (harmless
// at 1 wave/SIMD).
// Garbage rows (r<0, r>1023) carry PADV-scale costs acting as +inf.
// Lane 63 writes c3 (row r = t-63) to bnd[wv+1][r+BOFF] = [64tc+4+s] each
// step (others hit a dump sink, branchless); monotone chunk-counter
// handshake with lag 2 (consumer chunk tc reads rows <= 64tc+64).
__global__ __launch_bounds__(256) void dtw_pl_kernel(const float* __restrict__ q,
                                                     const float* __restrict__ kk,
                                                     float* __restrict__ dists) {
    __shared__ float xl[XLEN];
    __shared__ float bnd[NW + 1][BSTRIDE];  // bnd[0] = BIGV region for wave 0
    __shared__ float dump[128];             // sink, indices up to 125 (R8 lesson)
    __shared__ int flagsA[NW + 1];          // [0]=sentinel; [w+1]=wave w chunks done
    const int tid = threadIdx.x;
    const int lane = tid & 63;
    const int wv = tid >> 6;
    const int pair = blockIdx.x;            // 0..63
    const float* __restrict__ x = q + (pair >> 3) * SEGLEN;
    const float* __restrict__ y = kk + (pair & 7) * SEGLEN;

    for (int t = tid; t < XLEN; t += 256) xl[t] = (t < SEGLEN) ? x[t] : PADV;
    // flat index 66 = bnd[0][BOFF-1] = virtual corner D[-1,-1] = 0; rest BIGV.
    for (int t = tid; t < (NW + 1) * BSTRIDE; t += 256)
        (&bnd[0][0])[t] = (t == BOFF - 1) ? 0.f : BIGV;
    if (tid < NW + 1) flagsA[tid] = (tid == 0) ? 0x7FFFFFFF : 0;

    const float4 y4 = *(const float4*)(y + wv * 256 + lane * 4);
    const float yv0 = y4.x, yv1 = y4.y, yv2 = y4.z, yv3 = y4.w;

    __syncthreads();   // the only block-wide barrier

    const float* __restrict__ br = &bnd[wv][0];   // left neighbor's boundary

    // wait for the first 2 producer chunks before reading init boundary
    {
        const int need0 = (NCH < 2) ? NCH : 2;
        while (__hip_atomic_load(&flagsA[wv], __ATOMIC_ACQUIRE,
                                 __HIP_MEMORY_SCOPE_WORKGROUP) < need0)
            __builtin_amdgcn_s_sleep(1);
    }
    float P0 = BIGV, P1 = BIGV, P2 = BIGV, P3 = BIGV, xreg = PADV;
    float lf = br[BOFF];       // D[0, 256w-1] (wave 0: BIGV); real only lane 0
    float dgl = br[BOFF - 1];  // D[-1,256w-1] (wave 0: corner 0)

// One systolic step; inject values come straight from the preloaded
// register arrays (static index s) as DPP old-operands.
#define STEP(s) {                                                             \
    xreg = WSHIFT1(x64u[(s)], xreg);                                          \
    const float c0n = fabsf(xreg - yv0) + fminf(fminf(P0, lf), dgl);          \
    const float c1n = fabsf(xreg - yv1) + fminf(fminf(P1, c0n), P0);          \
    const float c2n = fabsf(xreg - yv2) + fminf(fminf(P2, c1n), P1);          \
    const float c3n = fabsf(xreg - yv3) + fminf(fminf(P3, c2n), P2);          \
    const float n1 = WSHIFT1(b64[(s)], c3n);                                  \
    dgl = lf; lf = n1; P0 = c0n; P1 = c1n; P2 = c2n; P3 = c3n;                \
    va[(s)] = c3n;                                                            \
}
#define STEP8(s) STEP(s) STEP((s)+1) STEP((s)+2) STEP((s)+3)                  \
                 STEP((s)+4) STEP((s)+5) STEP((s)+6) STEP((s)+7)

#pragma unroll 1
    for (int tc = 0; tc < NCH; ++tc) {
        // consumer chunk tc reads bnd rows <= 64tc+64; producer writes row r
        // at its step r+63 -> needs chunk tc+1 done (flag >= tc+2), capped
        // at NCH (later indices are BIGV pad).
        const int need = (tc + 2 < NCH) ? (tc + 2) : NCH;
        while (__hip_atomic_load(&flagsA[wv], __ATOMIC_ACQUIRE,
                                 __HIP_MEMORY_SCOPE_WORKGROUP) < need)
            __builtin_amdgcn_s_sleep(1);

        // uniform preloads (16B-aligned, broadcast reads, no conflicts):
        // x64u[s] = x[64tc+s]; b64[s] = bnd row 64tc+s+1 (index 64tc+68+s).
        float x64u[64], b64[64];
#pragma unroll
        for (int j = 0; j < 16; ++j)
            *(float4*)&x64u[4 * j] = *(const float4*)&xl[64 * tc + 4 * j];
#pragma unroll
        for (int j = 0; j < 16; ++j)
            *(float4*)&b64[4 * j] = *(const float4*)&br[64 * tc + 68 + 4 * j];

        // boundary write: lane 63 (row r = 64tc+s-63) -> bnd[wv+1][64tc+4+s];
        // others -> dump.
        float* va = (lane == 63) ? &bnd[wv + 1][64 * tc + 4] : &dump[lane];

        STEP8(0) STEP8(8) STEP8(16) STEP8(24) STEP8(32) STEP8(40) STEP8(48) STEP8(56)

        // publish chunk tc (release orders the ds_writes above before the flag)
        __hip_atomic_store(&flagsA[wv + 1], tc + 1, __ATOMIC_RELEASE,
                           __HIP_MEMORY_SCOPE_WORKGROUP);
    }
#undef STEP
#undef STEP8

    // D[1023,1023]: wave 3 lane 63 col e=3 at t=1086 (chunk 16, s=62) -> c3
    // -> bnd[NW][1023+BOFF] = bnd[NW][1090]; read back from LDS.
    if (wv == NW - 1 && lane == 0) dists[pair] = bnd[NW][1090];
}

// out[i*1024+p] = sum_j softmax_j(0.5*dists[i,:])[j] * values[j*1024+p]
__global__ __launch_bounds__(256) void softmax_out_kernel(const float* __restrict__ v,
                                                          const float* __restrict__ dists,
                                                          float* __restrict__ out) {
    const int o = blockIdx.x * blockDim.x + threadIdx.x;
    if (o >= NSEG * SEGLEN) return;
    const int i = o >> 10;
    const int p = o & 1023;

    float l[NSEG];
    float mx = -FLT_MAX;
#pragma unroll
    for (int j = 0; j < NSEG; ++j) {
        l[j] = 0.5f * dists[i * NSEG + j];
        mx = fmaxf(mx, l[j]);
    }
    float s = 0.f;
#pragma unroll
    for (int j = 0; j < NSEG; ++j) {
        l[j] = expf(l[j] - mx);
        s += l[j];
    }
    const float inv = 1.f / s;
    float acc = 0.f;
#pragma unroll
    for (int j = 0; j < NSEG; ++j) acc += (l[j] * inv) * v[j * SEGLEN + p];
    out[o] = acc;
}

extern "C" void kernel_launch(void* const* d_in, const int* in_sizes, int n_in,
                              void* d_out, int out_size, void* d_ws, size_t ws_size,
                              hipStream_t stream) {
    const float* q = (const float*)d_in[0];   // queries [1,32,8,32] f32
    const float* k = (const float*)d_in[1];   // keys
    const float* v = (const float*)d_in[2];   // values
    float* out = (float*)d_out;               // [8192] f32
    float* dists = (float*)d_ws;              // 64 floats scratch

    dtw_pl_kernel<<<dim3(NSEG * NSEG), dim3(256), 0, stream>>>(q, k, dists);
    softmax_out_kernel<<<dim3((NSEG * SEGLEN + 255) / 256), dim3(256), 0, stream>>>(v, dists, out);
}